// Round 5
// baseline (248.882 us; speedup 1.0000x reference)
//
#include <hip/hip_runtime.h>

#define N_B   262144
#define BM    128      // proven best tile; 2 blocks/CU
#define KAUG  288      // 256 (h) + 32 (x-augmentation, only 3 used)
#define LDA   264      // hA row stride in halves: 528B; 132 dw = 4 mod 32 -> 2-way bank alias (free)

typedef _Float16 f16x8 __attribute__((ext_vector_type(8)));
typedef _Float16 f16x4 __attribute__((ext_vector_type(4)));
typedef float    f32x4 __attribute__((ext_vector_type(4)));
typedef float    f32x16 __attribute__((ext_vector_type(16)));

// ---------------------------------------------------------------------------
// Precompute (68 blocks, ~5 us):
//   blocks 0..63 : (l = b>>4, row-group ng = b&15) -> Mt[l][16ng..16ng+16)[*]
//   blocks 64..67: W1t[n][k] = W1[k][n] transpose.
// ---------------------------------------------------------------------------
__global__ void fno_precompute(const float* __restrict__ W1,
                               const float* __restrict__ fw,
                               const float* __restrict__ lw,
                               _Float16* __restrict__ Mt,    // [4][256][KAUG]
                               _Float16* __restrict__ W1t)   // [256][64]
{
    const int t = threadIdx.x;          // 0..255
    const int b = blockIdx.x;
    if (b < 64) {
        const int l  = b >> 4;
        const int ng = b & 15;
        __shared__ float cosTab[256];
        __shared__ float cs[256];
        cosTab[t] = cosf((float)t * (6.28318530717958647692f / 256.0f));
        __syncthreads();
        // cs[t] = irfft(fw_l)[t]
        {
            const float* fwl = fw + l * 129;
            float s = fwl[0];
            #pragma unroll 4
            for (int k = 1; k < 128; ++k)
                s += 2.0f * fwl[k] * cosTab[(k * t) & 255];
            s += fwl[128] * ((t & 1) ? -1.0f : 1.0f);
            cs[t] = s * (1.0f / 256.0f);
        }
        __syncthreads();
        for (int idx = t; idx < 16 * KAUG; idx += 256) {
            const int n = ng * 16 + idx / KAUG;
            const int k = idx % KAUG;
            float v = 0.0f;
            if (k < 253)               v = cs[(n - k - 3) & 255];  // conv: h[k] -> d[k+3]
            if (k == n)                v += lw[l * 256 + n];       // diagonal residual lw
            if (k >= 256 && k < 259)   v = cs[(n - (k - 256)) & 255]; // x rows
            Mt[((size_t)l * 256 + n) * KAUG + k] = (_Float16)v;
        }
    } else {
        const int base = (b - 64) * 4096;
        #pragma unroll
        for (int i = 0; i < 16; ++i) {
            const int idx = base + t + i * 256;
            const int n = idx >> 6, k = idx & 63;
            W1t[idx] = (_Float16)W1[k * 256 + n];
        }
    }
}

// ---------------------------------------------------------------------------
// Fused main kernel. Block = 128 rows x 256 threads (4 waves); wave w owns
// feature columns [64w, 64w+64). 2 blocks/CU (LDS 70.7 KB).
// NEW vs 162us baseline: 32x32x16 MFMA instead of 16x16x32.
//   - +20% matrix-pipe FLOP/cyc (4061 vs 3378, m119/m06 HW ceilings)
//   - half the MFMA instructions (144 vs 288 per layer) -> fewer waitcnt
//     boundaries; 2 mfrag loads per K-group (vs 4) -> pipelining headroom
//     without the register spill that killed the R3 manual rotate.
// Operand layout (guide m74/m101): A/B: idx=lane&31, k=8*(lane>>5)+e (f16x8);
// D: col(=h-row)=lane&31, feat=(reg&3)+8*(reg>>2)+4*(lane>>5) + 32*ftile.
// x-augmentation in hA cols 256..258 (pad): kc=16,17 read cols 256..287 =
// x + zeros + next-row over-read hitting exactly-zero Mt weights; pad row BM
// is zeroed so row 127's over-read never sees uninit LDS.
// No manual prefetch rotate (R3: spilled at 21B/thread). Compiler schedules.
// ---------------------------------------------------------------------------
__global__ __launch_bounds__(256, 2)
void fno_main(const float* __restrict__ mu,
              const float* __restrict__ x,
              const float* __restrict__ b1,
              const float* __restrict__ W2,
              const float* __restrict__ b2,
              const _Float16* __restrict__ Mt,
              const _Float16* __restrict__ W1t,
              float* __restrict__ out)
{
    __shared__ __align__(16) _Float16 hA[(BM + 1) * LDA];  // h state + x cols + pad row
    __shared__ float b1s[256];
    __shared__ float W2s[256];
    __shared__ float red[BM];

    const int t    = threadIdx.x;
    const int w    = t >> 6;        // wave id: feature stripe 64*w
    const int lane = t & 63;
    const int i32  = lane & 31;     // operand index: h-row / Mt-feat
    const int q2   = lane >> 5;     // k-half within a K=16 chunk
    const int r0   = blockIdx.x * BM;
    const int hoff = i32 * LDA + 8 * q2;   // hfrag base offset (halves)

    // ---- stage mu -> hA cols 0..63 (fp16); x -> cols 256..263; zero pad row ----
    {
        const float4* mu4 = (const float4*)mu + (size_t)r0 * 16;  // 16 float4 per row
        #pragma unroll
        for (int j = 0; j < 8; ++j) {
            int f = t + 256 * j;
            int row = f >> 4, c4 = f & 15;
            float4 v = mu4[f];
            f16x4 h;
            h[0] = (_Float16)v.x; h[1] = (_Float16)v.y;
            h[2] = (_Float16)v.z; h[3] = (_Float16)v.w;
            *(f16x4*)&hA[row * LDA + c4 * 4] = h;
        }
        if (t < BM) {
            const float* xp = x + (size_t)(r0 + t) * 3;
            f16x8 hx = {(_Float16)xp[0], (_Float16)xp[1], (_Float16)xp[2],
                        (_Float16)0, (_Float16)0, (_Float16)0,
                        (_Float16)0, (_Float16)0};
            *(f16x8*)&hA[t * LDA + 256] = hx;
        }
        if (t < 33) {              // 33 * 8 = 264 halves: the whole pad row
            f16x8 z8 = {};
            *(f16x8*)&hA[BM * LDA + 8 * t] = z8;
        }
        b1s[t] = b1[t];
        W2s[t] = W2[t];
    }
    __syncthreads();

    const f32x16 fz = {0.f,0.f,0.f,0.f, 0.f,0.f,0.f,0.f,
                       0.f,0.f,0.f,0.f, 0.f,0.f,0.f,0.f};
    f32x16 acc[2][4];   // [feature-tile(32)][row-tile(32)], 128 regs

    // ================= encoder: h = relu(mu @ W1 + b1), K = 64 =================
    #pragma unroll
    for (int ft = 0; ft < 2; ++ft)
        #pragma unroll
        for (int rt = 0; rt < 4; ++rt) acc[ft][rt] = fz;

    {
        const _Float16* W1p = W1t + (64 * w + i32) * 64 + 8 * q2;
        #pragma unroll
        for (int kc = 0; kc < 4; ++kc) {
            f16x8 mfrag[2];
            #pragma unroll
            for (int ft = 0; ft < 2; ++ft)
                mfrag[ft] = *(const f16x8*)(W1p + 32 * ft * 64 + 16 * kc);
            #pragma unroll
            for (int rt = 0; rt < 4; ++rt) {
                f16x8 hfrag = *(const f16x8*)&hA[hoff + 32 * rt * LDA + 16 * kc];
                #pragma unroll
                for (int ft = 0; ft < 2; ++ft)
                    acc[ft][rt] = __builtin_amdgcn_mfma_f32_32x32x16_f16(
                        mfrag[ft], hfrag, acc[ft][rt], 0, 0, 0);
            }
        }
    }
    __syncthreads();   // all reads of mu-region done before overwrite
    #pragma unroll
    for (int ft = 0; ft < 2; ++ft)
        #pragma unroll
        for (int rt = 0; rt < 4; ++rt) {
            const int row = 32 * rt + i32;
            #pragma unroll
            for (int rg = 0; rg < 4; ++rg) {
                const int fb = 64 * w + 32 * ft + 4 * q2 + 8 * rg;
                const float4 bias = *(const float4*)&b1s[fb];
                f16x4 hv;
                hv[0] = (_Float16)fmaxf(acc[ft][rt][4 * rg + 0] + bias.x, 0.f);
                hv[1] = (_Float16)fmaxf(acc[ft][rt][4 * rg + 1] + bias.y, 0.f);
                hv[2] = (_Float16)fmaxf(acc[ft][rt][4 * rg + 2] + bias.z, 0.f);
                hv[3] = (_Float16)fmaxf(acc[ft][rt][4 * rg + 3] + bias.w, 0.f);
                *(f16x4*)&hA[row * LDA + fb] = hv;
            }
        }

    // ================= 4 Fourier layers: h = relu([h|x] @ M_l) ================
    #pragma unroll 1
    for (int l = 0; l < 4; ++l) {
        __syncthreads();   // hA writes from previous stage visible
        #pragma unroll
        for (int ft = 0; ft < 2; ++ft)
            #pragma unroll
            for (int rt = 0; rt < 4; ++rt) acc[ft][rt] = fz;

        const _Float16* Mlp = Mt + (size_t)l * 256 * KAUG
                                 + (64 * w + i32) * KAUG + 8 * q2;
        #pragma unroll
        for (int kc = 0; kc < 18; ++kc) {
            f16x8 mfrag[2];
            #pragma unroll
            for (int ft = 0; ft < 2; ++ft)
                mfrag[ft] = *(const f16x8*)(Mlp + 32 * ft * KAUG + 16 * kc);
            #pragma unroll
            for (int rt = 0; rt < 4; ++rt) {
                // kc=16,17 read cols 256..287: x + zeros + next-row (zero weights)
                f16x8 hfrag = *(const f16x8*)&hA[hoff + 32 * rt * LDA + 16 * kc];
                #pragma unroll
                for (int ft = 0; ft < 2; ++ft)
                    acc[ft][rt] = __builtin_amdgcn_mfma_f32_32x32x16_f16(
                        mfrag[ft], hfrag, acc[ft][rt], 0, 0, 0);
            }
        }

        __syncthreads();   // all hA reads done before overwrite
        #pragma unroll
        for (int ft = 0; ft < 2; ++ft)
            #pragma unroll
            for (int rt = 0; rt < 4; ++rt) {
                const int row = 32 * rt + i32;
                #pragma unroll
                for (int rg = 0; rg < 4; ++rg) {
                    const int fb = 64 * w + 32 * ft + 4 * q2 + 8 * rg;
                    f16x4 hv;
                    hv[0] = (_Float16)fmaxf(acc[ft][rt][4 * rg + 0], 0.f);
                    hv[1] = (_Float16)fmaxf(acc[ft][rt][4 * rg + 1], 0.f);
                    hv[2] = (_Float16)fmaxf(acc[ft][rt][4 * rg + 2], 0.f);
                    hv[3] = (_Float16)fmaxf(acc[ft][rt][4 * rg + 3], 0.f);
                    *(f16x4*)&hA[row * LDA + fb] = hv;
                }
            }
    }

    // ================= decoder: out = h @ W2 + b2 =============================
    __syncthreads();
    {
        const int r  = t & 127;
        const int hf = t >> 7;        // two threads per row, half the columns each
        const int n0 = hf * 128;
        float s = 0.f;
        #pragma unroll
        for (int j = 0; j < 16; ++j) {
            f16x8 v = *(const f16x8*)&hA[r * LDA + n0 + 8 * j];
            const float* wp = &W2s[n0 + 8 * j];
            s += (float)v[0] * wp[0] + (float)v[1] * wp[1]
               + (float)v[2] * wp[2] + (float)v[3] * wp[3]
               + (float)v[4] * wp[4] + (float)v[5] * wp[5]
               + (float)v[6] * wp[6] + (float)v[7] * wp[7];
        }
        if (hf) red[r] = s;
        __syncthreads();
        if (!hf) out[r0 + r] = s + red[r] + b2[0];
    }
}

// ---------------------------------------------------------------------------
extern "C" void kernel_launch(void* const* d_in, const int* in_sizes, int n_in,
                              void* d_out, int out_size, void* d_ws, size_t ws_size,
                              hipStream_t stream) {
    const float* mu = (const float*)d_in[0];
    const float* x  = (const float*)d_in[1];
    const float* W1 = (const float*)d_in[2];
    const float* b1 = (const float*)d_in[3];
    const float* fw = (const float*)d_in[4];
    const float* lw = (const float*)d_in[5];
    const float* W2 = (const float*)d_in[6];
    const float* b2 = (const float*)d_in[7];
    float* out = (float*)d_out;

    _Float16* Mt  = (_Float16*)d_ws;
    _Float16* W1t = Mt + 4 * 256 * KAUG;

    fno_precompute<<<68, 256, 0, stream>>>(W1, fw, lw, Mt, W1t);
    fno_main<<<N_B / BM, 256, 0, stream>>>(mu, x, b1, W2, b2, Mt, W1t, out);
}